// Round 1
// baseline (2850.836 us; speedup 1.0000x reference)
//
#include <hip/hip_runtime.h>

constexpr int DFEAT = 64;
constexpr int KSTEPS = 10;
constexpr float ALPHA = 0.1f;

// ---- degree count: deg[col[e]] += 1 ----
__global__ void k_deg(const int* __restrict__ col, float* __restrict__ deg, int E) {
    int stride = gridDim.x * blockDim.x;
    for (int e = blockIdx.x * blockDim.x + threadIdx.x; e < E; e += stride)
        atomicAdd(&deg[col[e]], 1.0f);
}

// ---- deg -> deg^{-1/2} in place ----
__global__ void k_dinv(float* __restrict__ deg, int N) {
    int stride = gridDim.x * blockDim.x;
    for (int i = blockIdx.x * blockDim.x + threadIdx.x; i < N; i += stride) {
        float d = deg[i];
        deg[i] = (d > 0.0f) ? rsqrtf(d) : 0.0f;
    }
}

// ---- norm[e] = dinv[row[e]] * dinv[col[e]] ----
__global__ void k_norm(const int* __restrict__ row, const int* __restrict__ col,
                       const float* __restrict__ dinv, float* __restrict__ nrm, int E) {
    int stride = gridDim.x * blockDim.x;
    for (int e = blockIdx.x * blockDim.x + threadIdx.x; e < E; e += stride)
        nrm[e] = dinv[row[e]] * dinv[col[e]];
}

// ---- scatter: agg[col[e]*64 + d] += norm[e] * h[row[e]*64 + d] ----
// one wave (64 lanes) per edge: lane d handles feature d.
__global__ void k_scatter(const int* __restrict__ row, const int* __restrict__ col,
                          const float* __restrict__ nrm, const float* __restrict__ h,
                          float* __restrict__ agg, int E) {
    long total  = (long)E * DFEAT;
    long stride = (long)gridDim.x * blockDim.x;
    for (long t = (long)blockIdx.x * blockDim.x + threadIdx.x; t < total; t += stride) {
        int e = (int)(t >> 6);
        int d = (int)(t & 63);
        int r = row[e];
        int c = col[e];
        float v = nrm[e] * h[(long)r * DFEAT + d];
        atomicAdd(&agg[(long)c * DFEAT + d], v);
    }
}

// ---- h = 0.9*agg + 0.1*x  (vectorized float4) ----
__global__ void k_update(const float* __restrict__ agg, const float* __restrict__ x,
                         float* __restrict__ h, int n4) {
    const float4* a4 = (const float4*)agg;
    const float4* x4 = (const float4*)x;
    float4* h4 = (float4*)h;
    int stride = gridDim.x * blockDim.x;
    for (int i = blockIdx.x * blockDim.x + threadIdx.x; i < n4; i += stride) {
        float4 a = a4[i];
        float4 xx = x4[i];
        float4 o;
        o.x = (1.0f - ALPHA) * a.x + ALPHA * xx.x;
        o.y = (1.0f - ALPHA) * a.y + ALPHA * xx.y;
        o.z = (1.0f - ALPHA) * a.z + ALPHA * xx.z;
        o.w = (1.0f - ALPHA) * a.w + ALPHA * xx.w;
        h4[i] = o;
    }
}

extern "C" void kernel_launch(void* const* d_in, const int* in_sizes, int n_in,
                              void* d_out, int out_size, void* d_ws, size_t ws_size,
                              hipStream_t stream) {
    const float* x  = (const float*)d_in[0];
    const int*   ei = (const int*)d_in[1];
    const int N = in_sizes[0] / DFEAT;
    const int E = in_sizes[1] / 2;
    const int* row = ei;       // edge_index[0] = source
    const int* col = ei + E;   // edge_index[1] = target

    // workspace layout (256B aligned)
    char* ws = (char*)d_ws;
    auto align256 = [](size_t v) { return (v + 255) & ~(size_t)255; };
    float* deg = (float*)ws;
    size_t off = align256((size_t)N * sizeof(float));
    float* nrm = (float*)(ws + off);
    off += align256((size_t)E * sizeof(float));
    float* agg = (float*)(ws + off);

    float* h = (float*)d_out;   // h lives in d_out; fully rewritten every iter

    const int BLK = 256;
    const int gridE  = (E + BLK - 1) / BLK;                  // per-edge kernels
    const int gridN  = (N + BLK - 1) / BLK;                  // per-node kernel
    const int n4     = N * DFEAT / 4;
    const int gridU  = (n4 + BLK - 1) / BLK;                 // update kernel
    const int gridS  = 20480;                                // scatter: grid-stride

    hipMemsetAsync(deg, 0, (size_t)N * sizeof(float), stream);
    k_deg <<<gridE, BLK, 0, stream>>>(col, deg, E);
    k_dinv<<<gridN, BLK, 0, stream>>>(deg, N);
    k_norm<<<gridE, BLK, 0, stream>>>(row, col, deg, nrm, E);

    for (int k = 0; k < KSTEPS; ++k) {
        hipMemsetAsync(agg, 0, (size_t)N * DFEAT * sizeof(float), stream);
        const float* hsrc = (k == 0) ? x : h;
        k_scatter<<<gridS, BLK, 0, stream>>>(row, col, nrm, hsrc, agg, E);
        k_update <<<gridU, BLK, 0, stream>>>(agg, x, h, n4);
    }
}

// Round 2
// 1014.574 us; speedup vs baseline: 2.8099x; 2.8099x over previous
//
#include <hip/hip_runtime.h>

constexpr int DFEAT  = 64;
constexpr int KSTEPS = 10;
constexpr float ALPHA = 0.1f;

constexpr int SCAN_T    = 256;   // threads per scan block
constexpr int SCAN_I    = 4;     // items per thread
constexpr int SCAN_TILE = SCAN_T * SCAN_I;  // 1024

// ---- histogram: deg_int[col[e]] += 1 ----
__global__ void k_hist(const int* __restrict__ col, int* __restrict__ deg, int E) {
    int stride = gridDim.x * blockDim.x;
    for (int e = blockIdx.x * blockDim.x + threadIdx.x; e < E; e += stride)
        atomicAdd(&deg[col[e]], 1);
}

// ---- dinv[i] = deg>0 ? rsqrt(deg) : 0 ----
__global__ void k_dinv(const int* __restrict__ deg, float* __restrict__ dinv, int N) {
    int stride = gridDim.x * blockDim.x;
    for (int i = blockIdx.x * blockDim.x + threadIdx.x; i < N; i += stride) {
        int d = deg[i];
        dinv[i] = (d > 0) ? rsqrtf((float)d) : 0.0f;
    }
}

// ---- scan phase 1: per-block exclusive scan + block sums ----
__global__ void k_scan1(const int* __restrict__ in, int* __restrict__ out,
                        int* __restrict__ bsum, int n) {
    __shared__ int s[SCAN_T];
    int tid  = threadIdx.x;
    int base = blockIdx.x * SCAN_TILE + tid * SCAN_I;
    int v[SCAN_I];
    int sum = 0;
#pragma unroll
    for (int j = 0; j < SCAN_I; ++j) {
        v[j] = (base + j < n) ? in[base + j] : 0;
        sum += v[j];
    }
    s[tid] = sum;
    __syncthreads();
    for (int ofs = 1; ofs < SCAN_T; ofs <<= 1) {
        int t = (tid >= ofs) ? s[tid - ofs] : 0;
        __syncthreads();
        s[tid] += t;
        __syncthreads();
    }
    int excl = (tid == 0) ? 0 : s[tid - 1];
    if (tid == SCAN_T - 1) bsum[blockIdx.x] = s[tid];
#pragma unroll
    for (int j = 0; j < SCAN_I; ++j) {
        if (base + j < n) out[base + j] = excl;
        excl += v[j];
    }
}

// ---- scan phase 2: exclusive scan of block sums (small, single thread) ----
__global__ void k_scan2(int* __restrict__ bsum, int nb) {
    if (threadIdx.x == 0 && blockIdx.x == 0) {
        int acc = 0;
        for (int i = 0; i < nb; ++i) { int t = bsum[i]; bsum[i] = acc; acc += t; }
    }
}

// ---- scan phase 3: add block offset; write offs and cursor ----
__global__ void k_scan3(int* __restrict__ offs, int* __restrict__ cursor,
                        const int* __restrict__ bsum, int n) {
    int add  = bsum[blockIdx.x];
    int base = blockIdx.x * SCAN_TILE + threadIdx.x * SCAN_I;
#pragma unroll
    for (int j = 0; j < SCAN_I; ++j) {
        int i = base + j;
        if (i < n) { int o = offs[i] + add; offs[i] = o; cursor[i] = o; }
    }
}

// ---- fill CSR: srcs[pos] = row, norms[pos] = dinv[row]*dinv[col] ----
__global__ void k_fill(const int* __restrict__ row, const int* __restrict__ col,
                       const float* __restrict__ dinv, int* __restrict__ cursor,
                       int* __restrict__ srcs, float* __restrict__ norms, int E) {
    int stride = gridDim.x * blockDim.x;
    for (int e = blockIdx.x * blockDim.x + threadIdx.x; e < E; e += stride) {
        int r = row[e], c = col[e];
        int pos = atomicAdd(&cursor[c], 1);
        srcs[pos]  = r;
        norms[pos] = dinv[r] * dinv[c];
    }
}

// ---- propagate: one wave per dst node, lane = feature ----
__global__ void __launch_bounds__(256) k_prop(
    const int* __restrict__ offs, const int* __restrict__ deg,
    const int* __restrict__ srcs, const float* __restrict__ norms,
    const float* __restrict__ hsrc, const float* __restrict__ x,
    float* __restrict__ hdst, int N) {
    int wid  = (int)((blockIdx.x * blockDim.x + threadIdx.x) >> 6);
    int lane = threadIdx.x & 63;
    if (wid >= N) return;
    int start = offs[wid];
    int cnt   = deg[wid];
    float acc = 0.0f;
    if (cnt > 0) {
        int   s = srcs[start];
        float w = norms[start];
        for (int j = 0; j < cnt - 1; ++j) {
            int   sn = srcs[start + j + 1];      // prefetch next edge
            float wn = norms[start + j + 1];
            acc += w * hsrc[(long)s * DFEAT + lane];
            s = sn; w = wn;
        }
        acc += w * hsrc[(long)s * DFEAT + lane];
    }
    long o = (long)wid * DFEAT + lane;
    hdst[o] = (1.0f - ALPHA) * acc + ALPHA * x[o];
}

extern "C" void kernel_launch(void* const* d_in, const int* in_sizes, int n_in,
                              void* d_out, int out_size, void* d_ws, size_t ws_size,
                              hipStream_t stream) {
    const float* x  = (const float*)d_in[0];
    const int*   ei = (const int*)d_in[1];
    const int N = in_sizes[0] / DFEAT;
    const int E = in_sizes[1] / 2;
    const int* row = ei;       // sources
    const int* col = ei + E;   // destinations

    // workspace layout
    char* ws = (char*)d_ws;
    auto align256 = [](size_t v) { return (v + 255) & ~(size_t)255; };
    size_t off = 0;
    int* deg = (int*)(ws + off);        off += align256((size_t)N * 4);
    float* dinv = (float*)(ws + off);   off += align256((size_t)N * 4);
    int* offs = (int*)(ws + off);       off += align256((size_t)N * 4);
    int* cursor = (int*)(ws + off);     off += align256((size_t)N * 4);
    int* bsum = (int*)(ws + off);       off += align256((size_t)4096);
    int* srcs = (int*)(ws + off);       off += align256((size_t)E * 4);
    float* norms = (float*)(ws + off);  off += align256((size_t)E * 4);
    float* bufB = (float*)(ws + off);   off += align256((size_t)N * DFEAT * 4);

    float* out = (float*)d_out;

    const int BLK = 256;
    const int gridE = (E + BLK - 1) / BLK;
    const int gridN = (N + BLK - 1) / BLK;
    const int nb    = (N + SCAN_TILE - 1) / SCAN_TILE;
    const int gridP = (N * (DFEAT / 4) + (BLK / 4) - 1) / (BLK / 4) ; // N waves
    // N waves, 4 waves per 256-thread block:
    const int gridProp = (N + 3) / 4;

    hipMemsetAsync(deg, 0, (size_t)N * 4, stream);
    k_hist <<<gridE, BLK, 0, stream>>>(col, deg, E);
    k_dinv <<<gridN, BLK, 0, stream>>>(deg, dinv, N);
    k_scan1<<<nb, SCAN_T, 0, stream>>>(deg, offs, bsum, N);
    k_scan2<<<1, 64, 0, stream>>>(bsum, nb);
    k_scan3<<<nb, SCAN_T, 0, stream>>>(offs, cursor, bsum, N);
    k_fill <<<gridE, BLK, 0, stream>>>(row, col, dinv, cursor, srcs, norms, E);

    // ping-pong: k even -> dst=bufB, k odd -> dst=out; final (k=9, odd) lands in out
    for (int k = 0; k < KSTEPS; ++k) {
        const float* hsrc = (k == 0) ? x : ((k & 1) ? bufB : out);
        float*       hdst = (k & 1) ? out : bufB;
        k_prop<<<gridProp, BLK, 0, stream>>>(offs, deg, srcs, norms, hsrc, x, hdst, N);
    }
    (void)gridP; (void)ws_size; (void)n_in; (void)out_size;
}

// Round 3
// 761.110 us; speedup vs baseline: 3.7456x; 1.3330x over previous
//
#include <hip/hip_runtime.h>

constexpr int DFEAT  = 64;
constexpr int KSTEPS = 10;
constexpr float ALPHA = 0.1f;

constexpr int SCAN_T    = 256;
constexpr int SCAN_I    = 4;
constexpr int SCAN_TILE = SCAN_T * SCAN_I;  // 1024

// ---- histogram: deg[col[e]] += 1 ----
__global__ void k_hist(const int* __restrict__ col, int* __restrict__ deg, int E) {
    int stride = gridDim.x * blockDim.x;
    for (int e = blockIdx.x * blockDim.x + threadIdx.x; e < E; e += stride)
        atomicAdd(&deg[col[e]], 1);
}

// ---- dinv[i] = deg>0 ? rsqrt(deg) : 0 ----
__global__ void k_dinv(const int* __restrict__ deg, float* __restrict__ dinv, int N) {
    int stride = gridDim.x * blockDim.x;
    for (int i = blockIdx.x * blockDim.x + threadIdx.x; i < N; i += stride) {
        int d = deg[i];
        dinv[i] = (d > 0) ? rsqrtf((float)d) : 0.0f;
    }
}

// ---- scan phase 1 ----
__global__ void k_scan1(const int* __restrict__ in, int* __restrict__ out,
                        int* __restrict__ bsum, int n) {
    __shared__ int s[SCAN_T];
    int tid  = threadIdx.x;
    int base = blockIdx.x * SCAN_TILE + tid * SCAN_I;
    int v[SCAN_I];
    int sum = 0;
#pragma unroll
    for (int j = 0; j < SCAN_I; ++j) {
        v[j] = (base + j < n) ? in[base + j] : 0;
        sum += v[j];
    }
    s[tid] = sum;
    __syncthreads();
    for (int ofs = 1; ofs < SCAN_T; ofs <<= 1) {
        int t = (tid >= ofs) ? s[tid - ofs] : 0;
        __syncthreads();
        s[tid] += t;
        __syncthreads();
    }
    int excl = (tid == 0) ? 0 : s[tid - 1];
    if (tid == SCAN_T - 1) bsum[blockIdx.x] = s[tid];
#pragma unroll
    for (int j = 0; j < SCAN_I; ++j) {
        if (base + j < n) out[base + j] = excl;
        excl += v[j];
    }
}

// ---- scan phase 2 ----
__global__ void k_scan2(int* __restrict__ bsum, int nb) {
    if (threadIdx.x == 0 && blockIdx.x == 0) {
        int acc = 0;
        for (int i = 0; i < nb; ++i) { int t = bsum[i]; bsum[i] = acc; acc += t; }
    }
}

// ---- scan phase 3 ----
__global__ void k_scan3(int* __restrict__ offs, int* __restrict__ cursor,
                        const int* __restrict__ bsum, int n) {
    int add  = bsum[blockIdx.x];
    int base = blockIdx.x * SCAN_TILE + threadIdx.x * SCAN_I;
#pragma unroll
    for (int j = 0; j < SCAN_I; ++j) {
        int i = base + j;
        if (i < n) { int o = offs[i] + add; offs[i] = o; cursor[i] = o; }
    }
}

// ---- fill CSR: meta[pos] = {src, norm} ----
__global__ void k_fill(const int* __restrict__ row, const int* __restrict__ col,
                       const float* __restrict__ dinv, int* __restrict__ cursor,
                       int2* __restrict__ meta, int E) {
    int stride = gridDim.x * blockDim.x;
    for (int e = blockIdx.x * blockDim.x + threadIdx.x; e < E; e += stride) {
        int r = row[e], c = col[e];
        int pos = atomicAdd(&cursor[c], 1);
        int2 m;
        m.x = r;
        m.y = __float_as_int(dinv[r] * dinv[c]);
        meta[pos] = m;
    }
}

// ---- propagate: one wave per dst node, lane = feature, 4-way MLP unroll ----
__global__ void __launch_bounds__(256) k_prop(
    const int* __restrict__ offs, const int* __restrict__ deg,
    const int2* __restrict__ meta,
    const float* __restrict__ hsrc, const float* __restrict__ x,
    float* __restrict__ hdst, int N) {
    int wid  = (int)((blockIdx.x * blockDim.x + threadIdx.x) >> 6);
    int lane = threadIdx.x & 63;
    if (wid >= N) return;
    int j   = offs[wid];
    int end = j + deg[wid];

    float acc0 = 0.0f, acc1 = 0.0f, acc2 = 0.0f, acc3 = 0.0f;
    for (; j + 4 <= end; j += 4) {
        int2 m0 = meta[j];
        int2 m1 = meta[j + 1];
        int2 m2 = meta[j + 2];
        int2 m3 = meta[j + 3];
        float v0 = hsrc[((size_t)(unsigned)m0.x << 6) + lane];
        float v1 = hsrc[((size_t)(unsigned)m1.x << 6) + lane];
        float v2 = hsrc[((size_t)(unsigned)m2.x << 6) + lane];
        float v3 = hsrc[((size_t)(unsigned)m3.x << 6) + lane];
        acc0 += __int_as_float(m0.y) * v0;
        acc1 += __int_as_float(m1.y) * v1;
        acc2 += __int_as_float(m2.y) * v2;
        acc3 += __int_as_float(m3.y) * v3;
    }
    for (; j < end; ++j) {
        int2 m = meta[j];
        acc0 += __int_as_float(m.y) * hsrc[((size_t)(unsigned)m.x << 6) + lane];
    }
    float acc = (acc0 + acc1) + (acc2 + acc3);
    size_t o = ((size_t)wid << 6) + lane;
    hdst[o] = (1.0f - ALPHA) * acc + ALPHA * x[o];
}

extern "C" void kernel_launch(void* const* d_in, const int* in_sizes, int n_in,
                              void* d_out, int out_size, void* d_ws, size_t ws_size,
                              hipStream_t stream) {
    const float* x  = (const float*)d_in[0];
    const int*   ei = (const int*)d_in[1];
    const int N = in_sizes[0] / DFEAT;
    const int E = in_sizes[1] / 2;
    const int* row = ei;       // sources
    const int* col = ei + E;   // destinations

    char* ws = (char*)d_ws;
    auto align256 = [](size_t v) { return (v + 255) & ~(size_t)255; };
    size_t off = 0;
    int* deg = (int*)(ws + off);        off += align256((size_t)N * 4);
    float* dinv = (float*)(ws + off);   off += align256((size_t)N * 4);
    int* offs = (int*)(ws + off);       off += align256((size_t)N * 4);
    int* cursor = (int*)(ws + off);     off += align256((size_t)N * 4);
    int* bsum = (int*)(ws + off);       off += align256((size_t)4096);
    int2* meta = (int2*)(ws + off);     off += align256((size_t)E * 8);
    float* bufB = (float*)(ws + off);   off += align256((size_t)N * DFEAT * 4);

    float* out = (float*)d_out;

    const int BLK = 256;
    const int gridE = (E + BLK - 1) / BLK;
    const int gridN = (N + BLK - 1) / BLK;
    const int nb    = (N + SCAN_TILE - 1) / SCAN_TILE;
    const int gridProp = (N + 3) / 4;   // 4 waves per block, 1 wave per node

    hipMemsetAsync(deg, 0, (size_t)N * 4, stream);
    k_hist <<<gridE, BLK, 0, stream>>>(col, deg, E);
    k_dinv <<<gridN, BLK, 0, stream>>>(deg, dinv, N);
    k_scan1<<<nb, SCAN_T, 0, stream>>>(deg, offs, bsum, N);
    k_scan2<<<1, 64, 0, stream>>>(bsum, nb);
    k_scan3<<<nb, SCAN_T, 0, stream>>>(offs, cursor, bsum, N);
    k_fill <<<gridE, BLK, 0, stream>>>(row, col, dinv, cursor, meta, E);

    // ping-pong: final iteration (k=9, odd) lands in out
    for (int k = 0; k < KSTEPS; ++k) {
        const float* hsrc = (k == 0) ? x : ((k & 1) ? bufB : out);
        float*       hdst = (k & 1) ? out : bufB;
        k_prop<<<gridProp, BLK, 0, stream>>>(offs, deg, meta, hsrc, x, hdst, N);
    }
    (void)ws_size; (void)n_in; (void)out_size;
}